// Round 1
// baseline (764.964 us; speedup 1.0000x reference)
//
#include <hip/hip_runtime.h>

// LJ constants (sigma=1, eps=1, cutoff=5)
// SHIFT = 4*((1/5)^12 - (1/5)^6)
__device__ __constant__ float kShift = 4.0f * (float)(1.0 / 244140625.0 - 1.0 / 15625.0);

__device__ __forceinline__ float lj_half_e(float x, float y, float z) {
    float r2 = x * x + y * y + z * z;
    float inv_r2 = 1.0f / r2;
    float sr6 = inv_r2 * inv_r2 * inv_r2;   // (sigma/r)^6
    float sr12 = sr6 * sr6;
    float e = 4.0f * (sr12 - sr6) - kShift;
    return 0.5f * e;
}

// 4 edges per thread: distances read as 3x float4 (48 B = 4 edges * 12 B),
// indices as int4. Scatter via global atomicAdd (device-scope by default).
__global__ void lj_kernel(const float* __restrict__ dist,
                          const int* __restrict__ atom_a,
                          const int* __restrict__ atom_b,
                          float* __restrict__ out,
                          int n_edges) {
    int t = blockIdx.x * blockDim.x + threadIdx.x;
    long long e0 = (long long)t * 4;
    if (e0 >= n_edges) return;

    if (e0 + 3 < n_edges) {
        const float4* d4 = (const float4*)(dist) + (size_t)t * 3;
        float4 v0 = d4[0];
        float4 v1 = d4[1];
        float4 v2 = d4[2];
        int4 ia = ((const int4*)atom_a)[t];
        int4 ib = ((const int4*)atom_b)[t];

        float h0 = lj_half_e(v0.x, v0.y, v0.z);
        float h1 = lj_half_e(v0.w, v1.x, v1.y);
        float h2 = lj_half_e(v1.z, v1.w, v2.x);
        float h3 = lj_half_e(v2.y, v2.z, v2.w);

        atomicAdd(&out[ia.x], h0);
        atomicAdd(&out[ib.x], h0);
        atomicAdd(&out[ia.y], h1);
        atomicAdd(&out[ib.y], h1);
        atomicAdd(&out[ia.z], h2);
        atomicAdd(&out[ib.z], h2);
        atomicAdd(&out[ia.w], h3);
        atomicAdd(&out[ib.w], h3);
    } else {
        // tail (not hit for E=6.4M, kept for safety)
        for (long long e = e0; e < n_edges; ++e) {
            float x = dist[e * 3 + 0];
            float y = dist[e * 3 + 1];
            float z = dist[e * 3 + 2];
            float h = lj_half_e(x, y, z);
            atomicAdd(&out[atom_a[e]], h);
            atomicAdd(&out[atom_b[e]], h);
        }
    }
}

extern "C" void kernel_launch(void* const* d_in, const int* in_sizes, int n_in,
                              void* d_out, int out_size, void* d_ws, size_t ws_size,
                              hipStream_t stream) {
    const float* dist = (const float*)d_in[0];
    const int* atom_a = (const int*)d_in[1];
    const int* atom_b = (const int*)d_in[2];
    float* out = (float*)d_out;

    int n_edges = in_sizes[1];  // first_atom element count = E

    // d_out is poisoned with 0xAA before every timed launch — zero it.
    hipMemsetAsync(d_out, 0, (size_t)out_size * sizeof(float), stream);

    int n_quads = (n_edges + 3) / 4;
    int block = 256;
    int grid = (n_quads + block - 1) / block;
    lj_kernel<<<grid, block, 0, stream>>>(dist, atom_a, atom_b, out, n_edges);
}

// Round 2
// 729.779 us; speedup vs baseline: 1.0482x; 1.0482x over previous
//
#include <hip/hip_runtime.h>

// LJ constants (sigma=1, eps=1, cutoff=5)
// SHIFT = 4*((1/5)^12 - (1/5)^6)
__device__ __constant__ float kShift = 4.0f * (float)(1.0 / 244140625.0 - 1.0 / 15625.0);

__device__ __forceinline__ float lj_half_e(float x, float y, float z) {
    float r2 = x * x + y * y + z * z;
    float inv_r2 = 1.0f / r2;
    float sr6 = inv_r2 * inv_r2 * inv_r2;   // (sigma/r)^6
    float sr12 = sr6 * sr6;
    float e = 4.0f * (sr12 - sr6) - kShift;
    return 0.5f * e;
}

// Which XCD (chiplet) is this wave running on? 0..7 on MI355X.
// HW-verified (learn_hip m09): s_getreg(HW_REG_XCC_ID) returns 0-7.
__device__ __forceinline__ int xcc_id() {
    int x;
    asm volatile("s_getreg_b32 %0, hwreg(HW_REG_XCC_ID, 0, 4)" : "=s"(x));
    return x & 7;
}

// XCD-local atomic add: workgroup-scope atomics drop sc1 and execute in the
// local XCD's TCC (L2). Safe because each private copy is only ever touched
// by blocks on that XCD.
__device__ __forceinline__ void atomic_add_xcd(float* p, float v) {
    __hip_atomic_fetch_add(p, v, __ATOMIC_RELAXED, __HIP_MEMORY_SCOPE_WORKGROUP);
}

// Phase 1: 4 edges/thread, scatter half-energies into the per-XCD private
// copy of the per-atom accumulator (ws[xcc * n_atoms + idx]).
__global__ void lj_scatter_xcd(const float* __restrict__ dist,
                               const int* __restrict__ atom_a,
                               const int* __restrict__ atom_b,
                               float* __restrict__ ws_copies,
                               int n_atoms,
                               int n_edges) {
    int t = blockIdx.x * blockDim.x + threadIdx.x;
    long long e0 = (long long)t * 4;
    if (e0 >= n_edges) return;

    float* priv = ws_copies + (size_t)xcc_id() * (size_t)n_atoms;

    if (e0 + 3 < n_edges) {
        const float4* d4 = (const float4*)(dist) + (size_t)t * 3;
        float4 v0 = d4[0];
        float4 v1 = d4[1];
        float4 v2 = d4[2];
        int4 ia = ((const int4*)atom_a)[t];
        int4 ib = ((const int4*)atom_b)[t];

        float h0 = lj_half_e(v0.x, v0.y, v0.z);
        float h1 = lj_half_e(v0.w, v1.x, v1.y);
        float h2 = lj_half_e(v1.z, v1.w, v2.x);
        float h3 = lj_half_e(v2.y, v2.z, v2.w);

        atomic_add_xcd(&priv[ia.x], h0);
        atomic_add_xcd(&priv[ib.x], h0);
        atomic_add_xcd(&priv[ia.y], h1);
        atomic_add_xcd(&priv[ib.y], h1);
        atomic_add_xcd(&priv[ia.z], h2);
        atomic_add_xcd(&priv[ib.z], h2);
        atomic_add_xcd(&priv[ia.w], h3);
        atomic_add_xcd(&priv[ib.w], h3);
    } else {
        for (long long e = e0; e < n_edges; ++e) {
            float x = dist[e * 3 + 0];
            float y = dist[e * 3 + 1];
            float z = dist[e * 3 + 2];
            float h = lj_half_e(x, y, z);
            atomic_add_xcd(&priv[atom_a[e]], h);
            atomic_add_xcd(&priv[atom_b[e]], h);
        }
    }
}

// Phase 2: out[i] = sum over the 8 XCD-private copies.
__global__ void reduce_copies(const float* __restrict__ ws_copies,
                              float* __restrict__ out,
                              int n_atoms) {
    int i = (blockIdx.x * blockDim.x + threadIdx.x) * 4;
    if (i >= n_atoms) return;
    if (i + 3 < n_atoms) {
        float4 s = make_float4(0.f, 0.f, 0.f, 0.f);
        #pragma unroll
        for (int c = 0; c < 8; ++c) {
            float4 v = *(const float4*)(ws_copies + (size_t)c * n_atoms + i);
            s.x += v.x; s.y += v.y; s.z += v.z; s.w += v.w;
        }
        *(float4*)(out + i) = s;
    } else {
        for (; i < n_atoms; ++i) {
            float s = 0.f;
            for (int c = 0; c < 8; ++c) s += ws_copies[(size_t)c * n_atoms + i];
            out[i] = s;
        }
    }
}

// Fallback (ws too small): device-scope atomics straight into out. Correct, slow.
__global__ void lj_scatter_direct(const float* __restrict__ dist,
                                  const int* __restrict__ atom_a,
                                  const int* __restrict__ atom_b,
                                  float* __restrict__ out,
                                  int n_edges) {
    int t = blockIdx.x * blockDim.x + threadIdx.x;
    long long e0 = (long long)t * 4;
    if (e0 >= n_edges) return;
    if (e0 + 3 < n_edges) {
        const float4* d4 = (const float4*)(dist) + (size_t)t * 3;
        float4 v0 = d4[0];
        float4 v1 = d4[1];
        float4 v2 = d4[2];
        int4 ia = ((const int4*)atom_a)[t];
        int4 ib = ((const int4*)atom_b)[t];
        float h0 = lj_half_e(v0.x, v0.y, v0.z);
        float h1 = lj_half_e(v0.w, v1.x, v1.y);
        float h2 = lj_half_e(v1.z, v1.w, v2.x);
        float h3 = lj_half_e(v2.y, v2.z, v2.w);
        atomicAdd(&out[ia.x], h0);
        atomicAdd(&out[ib.x], h0);
        atomicAdd(&out[ia.y], h1);
        atomicAdd(&out[ib.y], h1);
        atomicAdd(&out[ia.z], h2);
        atomicAdd(&out[ib.z], h2);
        atomicAdd(&out[ia.w], h3);
        atomicAdd(&out[ib.w], h3);
    } else {
        for (long long e = e0; e < n_edges; ++e) {
            float x = dist[e * 3 + 0];
            float y = dist[e * 3 + 1];
            float z = dist[e * 3 + 2];
            float h = lj_half_e(x, y, z);
            atomicAdd(&out[atom_a[e]], h);
            atomicAdd(&out[atom_b[e]], h);
        }
    }
}

extern "C" void kernel_launch(void* const* d_in, const int* in_sizes, int n_in,
                              void* d_out, int out_size, void* d_ws, size_t ws_size,
                              hipStream_t stream) {
    const float* dist = (const float*)d_in[0];
    const int* atom_a = (const int*)d_in[1];
    const int* atom_b = (const int*)d_in[2];
    float* out = (float*)d_out;

    int n_edges = in_sizes[1];  // first_atom element count = E
    int n_atoms = out_size;     // output is per-atom energies

    const int NUM_COPIES = 8;   // one per XCD
    size_t need = (size_t)NUM_COPIES * (size_t)n_atoms * sizeof(float);

    int n_quads = (n_edges + 3) / 4;
    int block = 256;
    int grid = (n_quads + block - 1) / block;

    if (ws_size >= need) {
        float* ws_copies = (float*)d_ws;
        // ws is poisoned with 0xAA before every timed launch — zero the copies.
        hipMemsetAsync(d_ws, 0, need, stream);
        lj_scatter_xcd<<<grid, block, 0, stream>>>(dist, atom_a, atom_b,
                                                   ws_copies, n_atoms, n_edges);
        int rblock = 256;
        int rgrid = (n_atoms / 4 + rblock - 1) / rblock + 1;  // +1 covers tail
        reduce_copies<<<rgrid, rblock, 0, stream>>>(ws_copies, out, n_atoms);
    } else {
        hipMemsetAsync(d_out, 0, (size_t)n_atoms * sizeof(float), stream);
        lj_scatter_direct<<<grid, block, 0, stream>>>(dist, atom_a, atom_b, out, n_edges);
    }
}

// Round 3
// 202.515 us; speedup vs baseline: 3.7773x; 3.6036x over previous
//
#include <hip/hip_runtime.h>

// LJ constants (sigma=1, eps=1, cutoff=5)
// SHIFT = 4*((1/5)^12 - (1/5)^6)
__device__ __constant__ float kShift = 4.0f * (float)(1.0 / 244140625.0 - 1.0 / 15625.0);

#define GROUPS 4
#define MEMBERS 64                 // blocks per group; GRID = GROUPS*MEMBERS = 256 (1 block/CU)
#define BUCKET 25600               // atoms per group; 25600*4B = 100 KiB LDS (<=160 KiB/CU)
#define BLOCK_T 1024               // threads per block (16 waves)

__device__ __forceinline__ float lj_half_e(float x, float y, float z) {
    float r2 = x * x + y * y + z * z;
    float inv_r2 = 1.0f / r2;
    float sr6 = inv_r2 * inv_r2 * inv_r2;   // (sigma/r)^6
    float sr12 = sr6 * sr6;
    float e = 4.0f * (sr12 - sr6) - kShift;
    return 0.5f * e;
}

// Gather-style: each group of 64 blocks owns atom range [g*BUCKET, (g+1)*BUCKET).
// The 64 members partition ALL edges; endpoints inside the owned range are
// accumulated in an LDS bucket (LDS atomics only — NO global atomics).
// Each block then streams its bucket to ws[blockIdx][BUCKET].
__global__ __launch_bounds__(BLOCK_T) void lj_gather_group(
        const float* __restrict__ dist,
        const int* __restrict__ atom_a,
        const int* __restrict__ atom_b,
        float* __restrict__ ws,
        int n_atoms, int n_edges) {
    __shared__ float acc[BUCKET];

    const int g = blockIdx.x / MEMBERS;
    const int m = blockIdx.x % MEMBERS;
    const unsigned lo = (unsigned)(g * BUCKET);

    for (int i = threadIdx.x; i < BUCKET; i += BLOCK_T) acc[i] = 0.0f;
    __syncthreads();

    const long long quads = ((long long)n_edges + 3) / 4;
    const long long per = (quads + MEMBERS - 1) / MEMBERS;
    const long long q0 = (long long)m * per;
    const long long q1 = (q0 + per < quads) ? (q0 + per) : quads;

    for (long long q = q0 + threadIdx.x; q < q1; q += BLOCK_T) {
        long long e0 = q * 4;
        if (e0 + 3 < n_edges) {
            const float4* d4 = (const float4*)(dist) + (size_t)q * 3;
            float4 v0 = d4[0];
            float4 v1 = d4[1];
            float4 v2 = d4[2];
            int4 ia = ((const int4*)atom_a)[q];
            int4 ib = ((const int4*)atom_b)[q];

            float h0 = lj_half_e(v0.x, v0.y, v0.z);
            float h1 = lj_half_e(v0.w, v1.x, v1.y);
            float h2 = lj_half_e(v1.z, v1.w, v2.x);
            float h3 = lj_half_e(v2.y, v2.z, v2.w);

            unsigned r;
            r = (unsigned)ia.x - lo; if (r < BUCKET) atomicAdd(&acc[r], h0);
            r = (unsigned)ib.x - lo; if (r < BUCKET) atomicAdd(&acc[r], h0);
            r = (unsigned)ia.y - lo; if (r < BUCKET) atomicAdd(&acc[r], h1);
            r = (unsigned)ib.y - lo; if (r < BUCKET) atomicAdd(&acc[r], h1);
            r = (unsigned)ia.z - lo; if (r < BUCKET) atomicAdd(&acc[r], h2);
            r = (unsigned)ib.z - lo; if (r < BUCKET) atomicAdd(&acc[r], h2);
            r = (unsigned)ia.w - lo; if (r < BUCKET) atomicAdd(&acc[r], h3);
            r = (unsigned)ib.w - lo; if (r < BUCKET) atomicAdd(&acc[r], h3);
        } else {
            for (long long e = e0; e < n_edges; ++e) {
                float x = dist[e * 3 + 0];
                float y = dist[e * 3 + 1];
                float z = dist[e * 3 + 2];
                float h = lj_half_e(x, y, z);
                unsigned r;
                r = (unsigned)atom_a[e] - lo; if (r < BUCKET) atomicAdd(&acc[r], h);
                r = (unsigned)atom_b[e] - lo; if (r < BUCKET) atomicAdd(&acc[r], h);
            }
        }
    }
    __syncthreads();

    float* dst = ws + (size_t)blockIdx.x * BUCKET;
    for (int i = threadIdx.x; i < BUCKET; i += BLOCK_T) dst[i] = acc[i];
}

// out[a] = sum over the 64 member partials of a's group.
__global__ void reduce_groups(const float* __restrict__ ws,
                              float* __restrict__ out,
                              int n_atoms) {
    int i = blockIdx.x * blockDim.x + threadIdx.x;
    if (i >= n_atoms) return;
    int g = i / BUCKET;
    int off = i - g * BUCKET;
    const float* base = ws + ((size_t)g * MEMBERS) * BUCKET + off;
    float s = 0.0f;
    #pragma unroll 8
    for (int b = 0; b < MEMBERS; ++b) s += base[(size_t)b * BUCKET];
    out[i] = s;
}

// Fallback (ws too small): device-scope atomics straight into out. ~650 us but correct.
__global__ void lj_scatter_direct(const float* __restrict__ dist,
                                  const int* __restrict__ atom_a,
                                  const int* __restrict__ atom_b,
                                  float* __restrict__ out,
                                  int n_edges) {
    int t = blockIdx.x * blockDim.x + threadIdx.x;
    long long e0 = (long long)t * 4;
    if (e0 >= n_edges) return;
    if (e0 + 3 < n_edges) {
        const float4* d4 = (const float4*)(dist) + (size_t)t * 3;
        float4 v0 = d4[0];
        float4 v1 = d4[1];
        float4 v2 = d4[2];
        int4 ia = ((const int4*)atom_a)[t];
        int4 ib = ((const int4*)atom_b)[t];
        float h0 = lj_half_e(v0.x, v0.y, v0.z);
        float h1 = lj_half_e(v0.w, v1.x, v1.y);
        float h2 = lj_half_e(v1.z, v1.w, v2.x);
        float h3 = lj_half_e(v2.y, v2.z, v2.w);
        atomicAdd(&out[ia.x], h0);
        atomicAdd(&out[ib.x], h0);
        atomicAdd(&out[ia.y], h1);
        atomicAdd(&out[ib.y], h1);
        atomicAdd(&out[ia.z], h2);
        atomicAdd(&out[ib.z], h2);
        atomicAdd(&out[ia.w], h3);
        atomicAdd(&out[ib.w], h3);
    } else {
        for (long long e = e0; e < n_edges; ++e) {
            float x = dist[e * 3 + 0];
            float y = dist[e * 3 + 1];
            float z = dist[e * 3 + 2];
            float h = lj_half_e(x, y, z);
            atomicAdd(&out[atom_a[e]], h);
            atomicAdd(&out[atom_b[e]], h);
        }
    }
}

extern "C" void kernel_launch(void* const* d_in, const int* in_sizes, int n_in,
                              void* d_out, int out_size, void* d_ws, size_t ws_size,
                              hipStream_t stream) {
    const float* dist = (const float*)d_in[0];
    const int* atom_a = (const int*)d_in[1];
    const int* atom_b = (const int*)d_in[2];
    float* out = (float*)d_out;

    int n_edges = in_sizes[1];
    int n_atoms = out_size;

    size_t need = (size_t)GROUPS * MEMBERS * BUCKET * sizeof(float);  // 26.2 MB
    bool range_ok = ((long long)GROUPS * BUCKET >= (long long)n_atoms);

    if (ws_size >= need && range_ok) {
        float* ws = (float*)d_ws;
        lj_gather_group<<<GROUPS * MEMBERS, BLOCK_T, 0, stream>>>(
            dist, atom_a, atom_b, ws, n_atoms, n_edges);
        int rblock = 256;
        int rgrid = (n_atoms + rblock - 1) / rblock;
        reduce_groups<<<rgrid, rblock, 0, stream>>>(ws, out, n_atoms);
    } else {
        hipMemsetAsync(d_out, 0, (size_t)n_atoms * sizeof(float), stream);
        int n_quads = (n_edges + 3) / 4;
        int block = 256;
        int grid = (n_quads + block - 1) / block;
        lj_scatter_direct<<<grid, block, 0, stream>>>(dist, atom_a, atom_b, out, n_edges);
    }
}